// Round 14
// baseline (103.891 us; speedup 1.0000x reference)
//
#include <hip/hip_runtime.h>
#include <hip/hip_fp16.h>
#include <cstddef>
#include <cstdint>

static inline int divup(int a, int b) { return (a + b - 1) / b; }

#define CAP 64        // per-node bucket capacity; P(deg>=64) ~ 1e-19 for Poisson(16)
#define EPB 4096      // edges per bin-block (16/thread @ 256 threads)
#define BSH 8         // bucket shift: bucket = dst >> 8 (256 nodes/bucket)

typedef _Float16 h2v __attribute__((ext_vector_type(2)));

// fp16x2 dot with fp32 accumulate (v_dot2_f32_f16); fallback = unpack + 2 fmaf
__device__ inline float fdot2f(unsigned int a, unsigned int b, float c) {
#if __has_builtin(__builtin_amdgcn_fdot2)
    return __builtin_amdgcn_fdot2(__builtin_bit_cast(h2v, a),
                                  __builtin_bit_cast(h2v, b), c, false);
#else
    __half2 ha = __builtin_bit_cast(__half2, a);
    __half2 hb = __builtin_bit_cast(__half2, b);
    float2 fa = __half22float2(ha), fb = __half22float2(hb);
    return fmaf(fa.y, fb.y, fmaf(fa.x, fb.x, c));
#endif
}

// Phase 1: block-local binning. Edges sorted by coarse bucket into a 32KB LDS
// tile, then dumped COALESCED to the block's private staging region.
// Block NB (extra) packs W1/W2 into k-pair half2 (fused weight conversion).
__global__ __launch_bounds__(256) void k_bin(const int* __restrict__ src,
                                             const int* __restrict__ dst,
                                             int2* __restrict__ staging,
                                             int* __restrict__ runoff,
                                             int* __restrict__ runlen,
                                             const float* __restrict__ W1,
                                             const float* __restrict__ W2,
                                             unsigned int* __restrict__ w1p,
                                             unsigned int* __restrict__ w2p,
                                             int E, int nbuck, int NB) {
    const int t = threadIdx.x;
    const int blk = blockIdx.x;
    if (blk == NB) {                       // weight-packing block
        for (int i = t; i < 32 * 128 + 64 * 64; i += 256) {
            if (i < 32 * 128) {
                int kp = i >> 7, c = i & 127;
                __half2 h = __floats2half2_rn(W1[(size_t)(2 * kp) * 128 + c],
                                              W1[(size_t)(2 * kp + 1) * 128 + c]);
                w1p[i] = __builtin_bit_cast(unsigned int, h);
            } else {
                int j = i - 32 * 128;
                int kp = j >> 6, c = j & 63;
                __half2 h = __floats2half2_rn(W2[(size_t)(2 * kp) * 64 + c],
                                              W2[(size_t)(2 * kp + 1) * 64 + c]);
                w2p[j] = __builtin_bit_cast(unsigned int, h);
            }
        }
        return;
    }
    __shared__ int hist[256];
    __shared__ int scan[256];
    __shared__ int2 sstage[EPB];          // 32 KiB block-local sorted edges
    const int e0 = blk * EPB;

    int2 ed[16];
    int cb[16];
    #pragma unroll
    for (int j = 0; j < 16; ++j) {
        int idx = e0 + j * 256 + t;
        if (idx < E) {
            ed[j].x = src[idx];
            ed[j].y = dst[idx];
            cb[j] = ed[j].y >> BSH;
        } else {
            cb[j] = -1;
        }
    }
    hist[t] = 0;
    __syncthreads();
    #pragma unroll
    for (int j = 0; j < 16; ++j)
        if (cb[j] >= 0) atomicAdd(&hist[cb[j]], 1);
    __syncthreads();
    scan[t] = hist[t];
    __syncthreads();
    for (int d = 1; d < 256; d <<= 1) {
        int v = (t >= d) ? scan[t - d] : 0;
        __syncthreads();
        scan[t] += v;
        __syncthreads();
    }
    int base = scan[t] - hist[t];
    if (t < nbuck) {
        runoff[t * NB + blk] = base;
        runlen[t * NB + blk] = hist[t];
    }
    hist[t] = base;
    __syncthreads();
    #pragma unroll
    for (int j = 0; j < 16; ++j) {
        if (cb[j] >= 0) {
            int p = atomicAdd(&hist[cb[j]], 1);
            sstage[p] = ed[j];            // LDS scatter (cheap)
        }
    }
    __syncthreads();
    // coalesced dump: 32KB as int4 stream
    int4* gout = reinterpret_cast<int4*>(staging + (size_t)blk * EPB);
    const int4* sin = reinterpret_cast<const int4*>(sstage);
    for (int i = t; i < EPB / 2; i += 256) gout[i] = sin[i];
}

// Phase 2: one block per bucket. Process the NB runs directly (8 runs x 32
// lanes, coalesced). Each node's neighbor list is SPLIT BY SRC RANGE:
// src < half packed ascending from slot 0; src >= half packed descending from
// slot CAP-1. cnt[node] = nlo | (nhi << 16). Lets the agg kernels gather in
// two temporal phases, each with a 3.2MB working set that fits per-XCD L2.
__global__ __launch_bounds__(256) void k_build(const int2* __restrict__ staging,
                                               const int* __restrict__ runoff,
                                               const int* __restrict__ runlen,
                                               const float* __restrict__ x,
                                               unsigned short* __restrict__ eidx,
                                               int* __restrict__ cnt,
                                               float* __restrict__ dinv,
                                               __half* __restrict__ xh,
                                               int n, int NB, int half) {
    __shared__ int runbase_l[512];
    __shared__ int runlen_l[512];
    __shared__ int cnt_lo[256];
    __shared__ int cnt_hi[256];
    __shared__ float sdinv[256];
    const int t = threadIdx.x;
    const int b = blockIdx.x;
    const int node0 = b << BSH;

    for (int r = t; r < NB; r += 256) {
        runbase_l[r] = runoff[b * NB + r];
        runlen_l[r]  = runlen[b * NB + r];
    }
    cnt_lo[t] = 0;
    cnt_hi[t] = 0;
    __syncthreads();
    const int lane = t & 31;
    for (int rb = t >> 5; rb < NB; rb += 8) {      // 8 runs in parallel, 32 lanes each
        const int2* sp = staging + (size_t)rb * EPB + runbase_l[rb];
        const int len = runlen_l[rb];
        for (int i = lane; i < len; i += 32) {
            int2 ed = sp[i];
            int local = ed.y - node0;
            if (ed.x < half) {
                int p = atomicAdd(&cnt_lo[local], 1);
                if (p < CAP) eidx[(size_t)ed.y * CAP + p] = (unsigned short)ed.x;
            } else {
                int p = atomicAdd(&cnt_hi[local], 1);
                if (p < CAP) eidx[(size_t)ed.y * CAP + (CAP - 1 - p)] = (unsigned short)ed.x;
            }
        }
    }
    __syncthreads();
    int node = node0 + t;
    int nlo = cnt_lo[t], nhi = cnt_hi[t];
    float di_t = rsqrtf((float)(nlo + nhi + 1));
    sdinv[t] = di_t;
    if (node < n) {
        cnt[node] = nlo | (nhi << 16);
        dinv[node] = di_t;
    }
    __syncthreads();
    for (int i = t; i < 256 * 16; i += 256) {
        int lr = i >> 4, c4 = (i & 15) * 4;
        int nd = node0 + lr;
        if (nd < n) {
            float4 v = *reinterpret_cast<const float4*>(x + (size_t)nd * 64 + c4);
            float di = sdinv[lr];
            __half2 h0 = __floats2half2_rn(v.x * di, v.y * di);
            __half2 h1 = __floats2half2_rn(v.z * di, v.w * di);
            *reinterpret_cast<__half2*>(xh + (size_t)nd * 64 + c4)     = h0;
            *reinterpret_cast<__half2*>(xh + (size_t)nd * 64 + c4 + 2) = h1;
        }
    }
}

__device__ inline void acc8(uint4 u, float a[8]) {
    float2 f0 = __half22float2(*reinterpret_cast<const __half2*>(&u.x));
    float2 f1 = __half22float2(*reinterpret_cast<const __half2*>(&u.y));
    float2 f2 = __half22float2(*reinterpret_cast<const __half2*>(&u.z));
    float2 f3 = __half22float2(*reinterpret_cast<const __half2*>(&u.w));
    a[0] += f0.x; a[1] += f0.y; a[2] += f1.x; a[3] += f1.y;
    a[4] += f2.x; a[5] += f2.y; a[6] += f3.x; a[7] += f3.y;
}

// accumulate gathered rows for index range [e, eN) of eidx (u16), 16B/lane
__device__ inline void gather_range(const unsigned short* __restrict__ eidx,
                                    const __half* __restrict__ in16,
                                    int hoff, int e, int eN, float a[8]) {
    // scalar-step until e is 4-aligned (uint2 load of eidx needs 8B alignment)
    while (e < eN && (e & 3)) {
        int s = eidx[e++];
        acc8(*reinterpret_cast<const uint4*>(in16 + (size_t)s * 64 + hoff), a);
    }
    for (; e + 4 <= eN; e += 4) {
        uint2 u = *reinterpret_cast<const uint2*>(eidx + e);   // 4 uint16 indices
        int s0 = u.x & 0xFFFF, s1 = u.x >> 16;
        int s2 = u.y & 0xFFFF, s3 = u.y >> 16;
        uint4 u0 = *reinterpret_cast<const uint4*>(in16 + (size_t)s0 * 64 + hoff);
        uint4 u1 = *reinterpret_cast<const uint4*>(in16 + (size_t)s1 * 64 + hoff);
        uint4 u2 = *reinterpret_cast<const uint4*>(in16 + (size_t)s2 * 64 + hoff);
        uint4 u3 = *reinterpret_cast<const uint4*>(in16 + (size_t)s3 * 64 + hoff);
        acc8(u0, a); acc8(u1, a); acc8(u2, a); acc8(u3, a);
    }
    for (; e < eN; ++e) {
        int s = eidx[e];
        acc8(*reinterpret_cast<const uint4*>(in16 + (size_t)s * 64 + hoff), a);
    }
}

// Row-parallel aggregation over fp16 64-col data: 8 lanes/node, 16B/lane.
// Two temporal gather phases (low-src rows then high-src rows) so each phase's
// working set (3.2MB) fits per-XCD L2.
// FINAL=false: axh(fp16) = (self + sum_neighbors) * dinv       (layer-1 pre-GEMM)
// FINAL=true : out(fp32) = relu((self + sum) * dinv + bias)    (layer-2 output)
template <bool FINAL>
__global__ __launch_bounds__(256) void k_aggh(const int* __restrict__ cnt,
                                              const unsigned short* __restrict__ eidx,
                                              const __half* __restrict__ in16,
                                              const float* __restrict__ dinv,
                                              const float* __restrict__ bias,
                                              void* __restrict__ outp, int n) {
    int t = blockIdx.x * blockDim.x + threadIdx.x;
    int node = t >> 3;
    if (node >= n) return;
    int lane = t & 7;
    const int hoff = lane * 8;
    float a[8] = {0.f, 0.f, 0.f, 0.f, 0.f, 0.f, 0.f, 0.f};
    acc8(*reinterpret_cast<const uint4*>(in16 + (size_t)node * 64 + hoff), a);  // self
    int c = cnt[node];
    int nlo = c & 0xFFFF, nhi = c >> 16;
    if (nlo > CAP) nlo = CAP;
    if (nlo + nhi > CAP) nhi = CAP - nlo;          // defensive (deg > CAP)
    const int b = node * CAP;
    gather_range(eidx, in16, hoff, b, b + nlo, a);             // phase A: low-src rows
    gather_range(eidx, in16, hoff, b + CAP - nhi, b + CAP, a); // phase B: high-src rows
    float di = dinv[node];
    if (FINAL) {
        float* out64 = (float*)outp;
        float4 r0, r1;
        const float4 b0 = *reinterpret_cast<const float4*>(bias + hoff);
        const float4 b1 = *reinterpret_cast<const float4*>(bias + hoff + 4);
        r0.x = fmaxf(fmaf(a[0], di, b0.x), 0.f); r0.y = fmaxf(fmaf(a[1], di, b0.y), 0.f);
        r0.z = fmaxf(fmaf(a[2], di, b0.z), 0.f); r0.w = fmaxf(fmaf(a[3], di, b0.w), 0.f);
        r1.x = fmaxf(fmaf(a[4], di, b1.x), 0.f); r1.y = fmaxf(fmaf(a[5], di, b1.y), 0.f);
        r1.z = fmaxf(fmaf(a[6], di, b1.z), 0.f); r1.w = fmaxf(fmaf(a[7], di, b1.w), 0.f);
        *reinterpret_cast<float4*>(out64 + (size_t)node * 64 + hoff)     = r0;
        *reinterpret_cast<float4*>(out64 + (size_t)node * 64 + hoff + 4) = r1;
    } else {
        unsigned int* out16 = (unsigned int*)outp;  // fp16 row-major, as uints
        __half2 p0 = __floats2half2_rn(a[0] * di, a[1] * di);
        __half2 p1 = __floats2half2_rn(a[2] * di, a[3] * di);
        __half2 p2 = __floats2half2_rn(a[4] * di, a[5] * di);
        __half2 p3 = __floats2half2_rn(a[6] * di, a[7] * di);
        uint4 o;
        o.x = __builtin_bit_cast(unsigned int, p0);
        o.y = __builtin_bit_cast(unsigned int, p1);
        o.z = __builtin_bit_cast(unsigned int, p2);
        o.w = __builtin_bit_cast(unsigned int, p3);
        *reinterpret_cast<uint4*>(out16 + (size_t)node * 32 + lane * 4) = o;
    }
}

// Fused MLP: hs2h = half( relu(axh @ W1 + b1) @ W2 * dinv[row] )
// 64-row block, 256 threads; fp16 operands (k-pair half2), fp32 accumulate.
// h1 never leaves LDS. Thread tile: layer1 4x8, layer2 4x4.
__global__ __launch_bounds__(256) void k_mlp(const __half* __restrict__ axh,
                                             const unsigned int* __restrict__ w1p,
                                             const unsigned int* __restrict__ w2p,
                                             const float* __restrict__ b1,
                                             const float* __restrict__ dinv,
                                             __half* __restrict__ hs2h, int n) {
    __shared__ unsigned int sW1[32 * 128];   // 16 KiB [kp][c]
    __shared__ unsigned int sW2[64 * 64];    // 16 KiB [kp][c]
    __shared__ unsigned int sA[32 * 68];     // 8.5 KiB [kp][row]
    __shared__ unsigned int sH[64 * 68];     // 17 KiB  [kp][row]
    const int t = threadIdx.x;
    const int r0 = blockIdx.x * 64;
    {
        uint4* d1 = reinterpret_cast<uint4*>(sW1);
        const uint4* s1 = reinterpret_cast<const uint4*>(w1p);
        for (int i = t; i < 1024; i += 256) d1[i] = s1[i];
        uint4* d2 = reinterpret_cast<uint4*>(sW2);
        const uint4* s2 = reinterpret_cast<const uint4*>(w2p);
        for (int i = t; i < 1024; i += 256) d2[i] = s2[i];
    }
    const unsigned int* axu = reinterpret_cast<const unsigned int*>(axh);
    for (int i = t; i < 2048; i += 256) {            // transpose A tile: [row][kp] -> [kp][row]
        int row = i >> 5, kp = i & 31;
        int gr = r0 + row;
        sA[kp * 68 + row] = (gr < n) ? axu[(size_t)gr * 32 + kp] : 0u;
    }
    __syncthreads();
    const int tx = t & 15, ty = t >> 4;
    float acc[4][8] = {};
    #pragma unroll 8
    for (int kp = 0; kp < 32; ++kp) {
        uint4 a4 = *reinterpret_cast<const uint4*>(&sA[kp * 68 + ty * 4]);
        uint4 wA = *reinterpret_cast<const uint4*>(&sW1[kp * 128 + tx * 4]);
        uint4 wB = *reinterpret_cast<const uint4*>(&sW1[kp * 128 + 64 + tx * 4]);
        unsigned int av[4] = {a4.x, a4.y, a4.z, a4.w};
        unsigned int wv[8] = {wA.x, wA.y, wA.z, wA.w, wB.x, wB.y, wB.z, wB.w};
        #pragma unroll
        for (int r = 0; r < 4; ++r)
            #pragma unroll
            for (int c = 0; c < 8; ++c)
                acc[r][c] = fdot2f(av[r], wv[c], acc[r][c]);
    }
    const float4 bb0 = *reinterpret_cast<const float4*>(b1 + tx * 4);
    const float4 bb1 = *reinterpret_cast<const float4*>(b1 + 64 + tx * 4);
    #pragma unroll
    for (int r = 0; r < 4; ++r) {
        int row = ty * 4 + r;
        float h0 = fmaxf(acc[r][0] + bb0.x, 0.f), h1 = fmaxf(acc[r][1] + bb0.y, 0.f);
        float h2 = fmaxf(acc[r][2] + bb0.z, 0.f), h3 = fmaxf(acc[r][3] + bb0.w, 0.f);
        float h4 = fmaxf(acc[r][4] + bb1.x, 0.f), h5 = fmaxf(acc[r][5] + bb1.y, 0.f);
        float h6 = fmaxf(acc[r][6] + bb1.z, 0.f), h7 = fmaxf(acc[r][7] + bb1.w, 0.f);
        __half2 p;
        p = __floats2half2_rn(h0, h1); sH[(2 * tx + 0) * 68 + row]  = __builtin_bit_cast(unsigned int, p);
        p = __floats2half2_rn(h2, h3); sH[(2 * tx + 1) * 68 + row]  = __builtin_bit_cast(unsigned int, p);
        p = __floats2half2_rn(h4, h5); sH[(32 + 2 * tx) * 68 + row] = __builtin_bit_cast(unsigned int, p);
        p = __floats2half2_rn(h6, h7); sH[(33 + 2 * tx) * 68 + row] = __builtin_bit_cast(unsigned int, p);
    }
    __syncthreads();
    float acc2[4][4] = {};
    #pragma unroll 8
    for (int kp = 0; kp < 64; ++kp) {
        uint4 a4 = *reinterpret_cast<const uint4*>(&sH[kp * 68 + ty * 4]);
        uint4 w4 = *reinterpret_cast<const uint4*>(&sW2[kp * 64 + tx * 4]);
        unsigned int av[4] = {a4.x, a4.y, a4.z, a4.w};
        unsigned int wv[4] = {w4.x, w4.y, w4.z, w4.w};
        #pragma unroll
        for (int r = 0; r < 4; ++r)
            #pragma unroll
            for (int c = 0; c < 4; ++c)
                acc2[r][c] = fdot2f(av[r], wv[c], acc2[r][c]);
    }
    #pragma unroll
    for (int r = 0; r < 4; ++r) {
        int row = r0 + ty * 4 + r;
        if (row < n) {
            float di = dinv[row];
            __half2 q0 = __floats2half2_rn(acc2[r][0] * di, acc2[r][1] * di);
            __half2 q1 = __floats2half2_rn(acc2[r][2] * di, acc2[r][3] * di);
            uint2 o;
            o.x = __builtin_bit_cast(unsigned int, q0);
            o.y = __builtin_bit_cast(unsigned int, q1);
            *reinterpret_cast<uint2*>(hs2h + (size_t)row * 64 + tx * 4) = o;
        }
    }
}

extern "C" void kernel_launch(void* const* d_in, const int* in_sizes, int n_in,
                              void* d_out, int out_size, void* d_ws, size_t ws_size,
                              hipStream_t stream) {
    const float* x  = (const float*)d_in[0];
    const int*   ei = (const int*)d_in[1];
    const float* W1 = (const float*)d_in[2];
    const float* b1 = (const float*)d_in[3];
    const float* W2 = (const float*)d_in[4];
    const float* b2 = (const float*)d_in[5];
    float* out = (float*)d_out;

    const int n = in_sizes[0] / 64;     // 50000 (< 65536 -> uint16 indices valid)
    const int E = in_sizes[1] / 2;      // 800000
    const int* src = ei;
    const int* dst = ei + E;

    const int NB = divup(E, EPB);         // 196 bin blocks
    const int nbuck = divup(n, 1 << BSH); // 196 buckets
    const int half = n / 2;               // src-range split for L2-resident phases

    char* ws = (char*)d_ws;
    size_t off = 0;
    auto alloc = [&](size_t bytes) { void* p = ws + off; off = (off + bytes + 255) & ~(size_t)255; return p; };
    int*    cnt     = (int*)   alloc((size_t)n * 4);
    float*  dinv    = (float*) alloc((size_t)n * 4);
    int2*   staging = (int2*)  alloc((size_t)NB * EPB * 8);   // 6.4 MB
    int*    runoff  = (int*)   alloc((size_t)nbuck * NB * 4);
    int*    runlen  = (int*)   alloc((size_t)nbuck * NB * 4);
    unsigned short* eidx = (unsigned short*)alloc((size_t)n * CAP * 2);  // 6.4 MB uint16
    __half* xh      = (__half*)alloc((size_t)n * 64 * 2);     // 6.4 MB fp16 payload
    __half* axh     = (__half*)alloc((size_t)n * 64 * 2);     // 6.4 MB aggregated x (fp16)
    unsigned int* w1p = (unsigned int*)alloc(32 * 128 * 4);
    unsigned int* w2p = (unsigned int*)alloc(64 * 64 * 4);
    __half* hs2h    = xh;     // xh dead after layer-1 agg; reuse (mlp r/w distinct rows 1:1)

    // adjacency build (+weight packing in extra block) + fused x*dinv -> fp16
    k_bin  <<<NB + 1, 256, 0, stream>>>(src, dst, staging, runoff, runlen, W1, W2, w1p, w2p, E, nbuck, NB);
    k_build<<<nbuck, 256, 0, stream>>>(staging, runoff, runlen, x, eidx, cnt, dinv, xh, n, NB, half);

    // layer 1 aggregate (fp16 out)
    k_aggh<false><<<divup(n * 8, 256), 256, 0, stream>>>(cnt, eidx, xh, dinv, nullptr, axh, n);

    // fused MLP: relu(axh@W1+b1)@W2 * dinv -> fp16
    k_mlp<<<divup(n, 64), 256, 0, stream>>>(axh, w1p, w2p, b1, dinv, hs2h, n);

    // layer 2 aggregate (fp32 out + bias + relu)
    k_aggh<true><<<divup(n * 8, 256), 256, 0, stream>>>(cnt, eidx, hs2h, dinv, b2, out, n);
}

// Round 15
// 100.115 us; speedup vs baseline: 1.0377x; 1.0377x over previous
//
#include <hip/hip_runtime.h>
#include <hip/hip_fp16.h>
#include <cstddef>
#include <cstdint>

static inline int divup(int a, int b) { return (a + b - 1) / b; }

#define CAP 64        // per-node bucket capacity; P(deg>=64) ~ 1e-19 for Poisson(16)
#define EPB 4096      // edges per bin-block (16/thread @ 256 threads)
#define BSH 8         // bucket shift: bucket = dst >> 8 (256 nodes/bucket)

typedef _Float16 h2v __attribute__((ext_vector_type(2)));

// fp16x2 dot with fp32 accumulate (v_dot2_f32_f16); fallback = unpack + 2 fmaf
__device__ inline float fdot2f(unsigned int a, unsigned int b, float c) {
#if __has_builtin(__builtin_amdgcn_fdot2)
    return __builtin_amdgcn_fdot2(__builtin_bit_cast(h2v, a),
                                  __builtin_bit_cast(h2v, b), c, false);
#else
    __half2 ha = __builtin_bit_cast(__half2, a);
    __half2 hb = __builtin_bit_cast(__half2, b);
    float2 fa = __half22float2(ha), fb = __half22float2(hb);
    return fmaf(fa.y, fb.y, fmaf(fa.x, fb.x, c));
#endif
}

// Phase 1: block-local binning. Edges sorted by coarse bucket into a 32KB LDS
// tile, then dumped COALESCED to the block's private staging region.
// Block NB (extra) packs W1/W2 into k-pair half2 (fused weight conversion).
__global__ __launch_bounds__(256) void k_bin(const int* __restrict__ src,
                                             const int* __restrict__ dst,
                                             int2* __restrict__ staging,
                                             int* __restrict__ runoff,
                                             int* __restrict__ runlen,
                                             const float* __restrict__ W1,
                                             const float* __restrict__ W2,
                                             unsigned int* __restrict__ w1p,
                                             unsigned int* __restrict__ w2p,
                                             int E, int nbuck, int NB) {
    const int t = threadIdx.x;
    const int blk = blockIdx.x;
    if (blk == NB) {                       // weight-packing block
        for (int i = t; i < 32 * 128 + 64 * 64; i += 256) {
            if (i < 32 * 128) {
                int kp = i >> 7, c = i & 127;
                __half2 h = __floats2half2_rn(W1[(size_t)(2 * kp) * 128 + c],
                                              W1[(size_t)(2 * kp + 1) * 128 + c]);
                w1p[i] = __builtin_bit_cast(unsigned int, h);
            } else {
                int j = i - 32 * 128;
                int kp = j >> 6, c = j & 63;
                __half2 h = __floats2half2_rn(W2[(size_t)(2 * kp) * 64 + c],
                                              W2[(size_t)(2 * kp + 1) * 64 + c]);
                w2p[j] = __builtin_bit_cast(unsigned int, h);
            }
        }
        return;
    }
    __shared__ int hist[256];
    __shared__ int scan[256];
    __shared__ int2 sstage[EPB];          // 32 KiB block-local sorted edges
    const int e0 = blk * EPB;

    int2 ed[16];
    int cb[16];
    #pragma unroll
    for (int j = 0; j < 16; ++j) {
        int idx = e0 + j * 256 + t;
        if (idx < E) {
            ed[j].x = src[idx];
            ed[j].y = dst[idx];
            cb[j] = ed[j].y >> BSH;
        } else {
            cb[j] = -1;
        }
    }
    hist[t] = 0;
    __syncthreads();
    #pragma unroll
    for (int j = 0; j < 16; ++j)
        if (cb[j] >= 0) atomicAdd(&hist[cb[j]], 1);
    __syncthreads();
    scan[t] = hist[t];
    __syncthreads();
    for (int d = 1; d < 256; d <<= 1) {
        int v = (t >= d) ? scan[t - d] : 0;
        __syncthreads();
        scan[t] += v;
        __syncthreads();
    }
    int base = scan[t] - hist[t];
    if (t < nbuck) {
        runoff[t * NB + blk] = base;
        runlen[t * NB + blk] = hist[t];
    }
    hist[t] = base;
    __syncthreads();
    #pragma unroll
    for (int j = 0; j < 16; ++j) {
        if (cb[j] >= 0) {
            int p = atomicAdd(&hist[cb[j]], 1);
            sstage[p] = ed[j];            // LDS scatter (cheap)
        }
    }
    __syncthreads();
    // coalesced dump: 32KB as int4 stream
    int4* gout = reinterpret_cast<int4*>(staging + (size_t)blk * EPB);
    const int4* sin = reinterpret_cast<const int4*>(sstage);
    for (int i = t; i < EPB / 2; i += 256) gout[i] = sin[i];
}

// Phase 2: one block per bucket. Process the NB runs directly (8 runs x 32
// lanes, coalesced — no scan, no binary search), scatter src into
// eidx16[node*CAP+p] (uint16, single-writer lines), emit cnt/dinv,
// fused xh = half(x * dinv).
__global__ __launch_bounds__(256) void k_build(const int2* __restrict__ staging,
                                               const int* __restrict__ runoff,
                                               const int* __restrict__ runlen,
                                               const float* __restrict__ x,
                                               unsigned short* __restrict__ eidx,
                                               int* __restrict__ cnt,
                                               float* __restrict__ dinv,
                                               __half* __restrict__ xh,
                                               int n, int NB) {
    __shared__ int runbase_l[512];
    __shared__ int runlen_l[512];
    __shared__ int cnt_l[256];
    __shared__ float sdinv[256];
    const int t = threadIdx.x;
    const int b = blockIdx.x;
    const int node0 = b << BSH;

    for (int r = t; r < NB; r += 256) {
        runbase_l[r] = runoff[b * NB + r];
        runlen_l[r]  = runlen[b * NB + r];
    }
    cnt_l[t] = 0;
    __syncthreads();
    const int lane = t & 31;
    for (int rb = t >> 5; rb < NB; rb += 8) {      // 8 runs in parallel, 32 lanes each
        const int2* sp = staging + (size_t)rb * EPB + runbase_l[rb];
        const int len = runlen_l[rb];
        for (int i = lane; i < len; i += 32) {
            int2 ed = sp[i];
            int p = atomicAdd(&cnt_l[ed.y - node0], 1);
            if (p < CAP) eidx[(size_t)ed.y * CAP + p] = (unsigned short)ed.x;
        }
    }
    __syncthreads();
    int node = node0 + t;
    float di_t = rsqrtf((float)(cnt_l[t] + 1));
    sdinv[t] = di_t;
    if (node < n) {
        cnt[node] = cnt_l[t];
        dinv[node] = di_t;
    }
    __syncthreads();
    for (int i = t; i < 256 * 16; i += 256) {
        int lr = i >> 4, c4 = (i & 15) * 4;
        int nd = node0 + lr;
        if (nd < n) {
            float4 v = *reinterpret_cast<const float4*>(x + (size_t)nd * 64 + c4);
            float di = sdinv[lr];
            __half2 h0 = __floats2half2_rn(v.x * di, v.y * di);
            __half2 h1 = __floats2half2_rn(v.z * di, v.w * di);
            *reinterpret_cast<__half2*>(xh + (size_t)nd * 64 + c4)     = h0;
            *reinterpret_cast<__half2*>(xh + (size_t)nd * 64 + c4 + 2) = h1;
        }
    }
}

__device__ inline void acc8(uint4 u, float a[8]) {
    float2 f0 = __half22float2(*reinterpret_cast<const __half2*>(&u.x));
    float2 f1 = __half22float2(*reinterpret_cast<const __half2*>(&u.y));
    float2 f2 = __half22float2(*reinterpret_cast<const __half2*>(&u.z));
    float2 f3 = __half22float2(*reinterpret_cast<const __half2*>(&u.w));
    a[0] += f0.x; a[1] += f0.y; a[2] += f1.x; a[3] += f1.y;
    a[4] += f2.x; a[5] += f2.y; a[6] += f3.x; a[7] += f3.y;
}

// Row-parallel aggregation over fp16 64-col data: 8 lanes/node, 16B/lane.
// FINAL=false: axh(fp16) = (self + sum_neighbors) * dinv       (layer-1 pre-GEMM)
// FINAL=true : out(fp32) = relu((self + sum) * dinv + bias)    (layer-2 output)
template <bool FINAL>
__global__ __launch_bounds__(256) void k_aggh(const int* __restrict__ cnt,
                                              const unsigned short* __restrict__ eidx,
                                              const __half* __restrict__ in16,
                                              const float* __restrict__ dinv,
                                              const float* __restrict__ bias,
                                              void* __restrict__ outp, int n) {
    int t = blockIdx.x * blockDim.x + threadIdx.x;
    int node = t >> 3;
    if (node >= n) return;
    int lane = t & 7;
    const int hoff = lane * 8;
    float a[8] = {0.f, 0.f, 0.f, 0.f, 0.f, 0.f, 0.f, 0.f};
    acc8(*reinterpret_cast<const uint4*>(in16 + (size_t)node * 64 + hoff), a);  // self
    const int b = node * CAP;
    const int eN = b + min(cnt[node], CAP);
    int e = b;
    for (; e + 4 <= eN; e += 4) {
        uint2 u = *reinterpret_cast<const uint2*>(eidx + e);   // 4 uint16 indices
        int s0 = u.x & 0xFFFF, s1 = u.x >> 16;
        int s2 = u.y & 0xFFFF, s3 = u.y >> 16;
        uint4 u0 = *reinterpret_cast<const uint4*>(in16 + (size_t)s0 * 64 + hoff);
        uint4 u1 = *reinterpret_cast<const uint4*>(in16 + (size_t)s1 * 64 + hoff);
        uint4 u2 = *reinterpret_cast<const uint4*>(in16 + (size_t)s2 * 64 + hoff);
        uint4 u3 = *reinterpret_cast<const uint4*>(in16 + (size_t)s3 * 64 + hoff);
        acc8(u0, a); acc8(u1, a); acc8(u2, a); acc8(u3, a);
    }
    for (; e < eN; ++e) {
        int s = eidx[e];
        acc8(*reinterpret_cast<const uint4*>(in16 + (size_t)s * 64 + hoff), a);
    }
    float di = dinv[node];
    if (FINAL) {
        float* out64 = (float*)outp;
        float4 r0, r1;
        const float4 b0 = *reinterpret_cast<const float4*>(bias + hoff);
        const float4 b1 = *reinterpret_cast<const float4*>(bias + hoff + 4);
        r0.x = fmaxf(fmaf(a[0], di, b0.x), 0.f); r0.y = fmaxf(fmaf(a[1], di, b0.y), 0.f);
        r0.z = fmaxf(fmaf(a[2], di, b0.z), 0.f); r0.w = fmaxf(fmaf(a[3], di, b0.w), 0.f);
        r1.x = fmaxf(fmaf(a[4], di, b1.x), 0.f); r1.y = fmaxf(fmaf(a[5], di, b1.y), 0.f);
        r1.z = fmaxf(fmaf(a[6], di, b1.z), 0.f); r1.w = fmaxf(fmaf(a[7], di, b1.w), 0.f);
        *reinterpret_cast<float4*>(out64 + (size_t)node * 64 + hoff)     = r0;
        *reinterpret_cast<float4*>(out64 + (size_t)node * 64 + hoff + 4) = r1;
    } else {
        unsigned int* out16 = (unsigned int*)outp;  // fp16 row-major, as uints
        __half2 p0 = __floats2half2_rn(a[0] * di, a[1] * di);
        __half2 p1 = __floats2half2_rn(a[2] * di, a[3] * di);
        __half2 p2 = __floats2half2_rn(a[4] * di, a[5] * di);
        __half2 p3 = __floats2half2_rn(a[6] * di, a[7] * di);
        uint4 o;
        o.x = __builtin_bit_cast(unsigned int, p0);
        o.y = __builtin_bit_cast(unsigned int, p1);
        o.z = __builtin_bit_cast(unsigned int, p2);
        o.w = __builtin_bit_cast(unsigned int, p3);
        *reinterpret_cast<uint4*>(out16 + (size_t)node * 32 + lane * 4) = o;
    }
}

// Fused MLP: hs2h = half( relu(axh @ W1 + b1) @ W2 * dinv[row] )
// 64-row block, 256 threads; fp16 operands (k-pair half2), fp32 accumulate.
// h1 never leaves LDS. sA and sH share one LDS buffer (sA dead after layer-1
// dot loop; extra barrier guards the overwrite) -> 49KB LDS, 3 blocks/CU.
__global__ __launch_bounds__(256) void k_mlp(const __half* __restrict__ axh,
                                             const unsigned int* __restrict__ w1p,
                                             const unsigned int* __restrict__ w2p,
                                             const float* __restrict__ b1,
                                             const float* __restrict__ dinv,
                                             __half* __restrict__ hs2h, int n) {
    __shared__ unsigned int sW1[32 * 128];   // 16 KiB [kp][c]
    __shared__ unsigned int sW2[64 * 64];    // 16 KiB [kp][c]
    __shared__ unsigned int sAH[64 * 68];    // 17 KiB union: sA (first 32*68) then sH
    const int t = threadIdx.x;
    const int r0 = blockIdx.x * 64;
    {
        uint4* d1 = reinterpret_cast<uint4*>(sW1);
        const uint4* s1 = reinterpret_cast<const uint4*>(w1p);
        for (int i = t; i < 1024; i += 256) d1[i] = s1[i];
        uint4* d2 = reinterpret_cast<uint4*>(sW2);
        const uint4* s2 = reinterpret_cast<const uint4*>(w2p);
        for (int i = t; i < 1024; i += 256) d2[i] = s2[i];
    }
    const unsigned int* axu = reinterpret_cast<const unsigned int*>(axh);
    for (int i = t; i < 2048; i += 256) {            // transpose A tile: [row][kp] -> [kp][row]
        int row = i >> 5, kp = i & 31;
        int gr = r0 + row;
        sAH[kp * 68 + row] = (gr < n) ? axu[(size_t)gr * 32 + kp] : 0u;
    }
    __syncthreads();
    const int tx = t & 15, ty = t >> 4;
    float acc[4][8] = {};
    #pragma unroll 8
    for (int kp = 0; kp < 32; ++kp) {
        uint4 a4 = *reinterpret_cast<const uint4*>(&sAH[kp * 68 + ty * 4]);
        uint4 wA = *reinterpret_cast<const uint4*>(&sW1[kp * 128 + tx * 4]);
        uint4 wB = *reinterpret_cast<const uint4*>(&sW1[kp * 128 + 64 + tx * 4]);
        unsigned int av[4] = {a4.x, a4.y, a4.z, a4.w};
        unsigned int wv[8] = {wA.x, wA.y, wA.z, wA.w, wB.x, wB.y, wB.z, wB.w};
        #pragma unroll
        for (int r = 0; r < 4; ++r)
            #pragma unroll
            for (int c = 0; c < 8; ++c)
                acc[r][c] = fdot2f(av[r], wv[c], acc[r][c]);
    }
    __syncthreads();                                 // all sA reads done before sH overwrite
    const float4 bb0 = *reinterpret_cast<const float4*>(b1 + tx * 4);
    const float4 bb1 = *reinterpret_cast<const float4*>(b1 + 64 + tx * 4);
    #pragma unroll
    for (int r = 0; r < 4; ++r) {
        int row = ty * 4 + r;
        float h0 = fmaxf(acc[r][0] + bb0.x, 0.f), h1 = fmaxf(acc[r][1] + bb0.y, 0.f);
        float h2 = fmaxf(acc[r][2] + bb0.z, 0.f), h3 = fmaxf(acc[r][3] + bb0.w, 0.f);
        float h4 = fmaxf(acc[r][4] + bb1.x, 0.f), h5 = fmaxf(acc[r][5] + bb1.y, 0.f);
        float h6 = fmaxf(acc[r][6] + bb1.z, 0.f), h7 = fmaxf(acc[r][7] + bb1.w, 0.f);
        __half2 p;
        p = __floats2half2_rn(h0, h1); sAH[(2 * tx + 0) * 68 + row]  = __builtin_bit_cast(unsigned int, p);
        p = __floats2half2_rn(h2, h3); sAH[(2 * tx + 1) * 68 + row]  = __builtin_bit_cast(unsigned int, p);
        p = __floats2half2_rn(h4, h5); sAH[(32 + 2 * tx) * 68 + row] = __builtin_bit_cast(unsigned int, p);
        p = __floats2half2_rn(h6, h7); sAH[(33 + 2 * tx) * 68 + row] = __builtin_bit_cast(unsigned int, p);
    }
    __syncthreads();
    float acc2[4][4] = {};
    #pragma unroll 8
    for (int kp = 0; kp < 64; ++kp) {
        uint4 a4 = *reinterpret_cast<const uint4*>(&sAH[kp * 68 + ty * 4]);
        uint4 w4 = *reinterpret_cast<const uint4*>(&sW2[kp * 64 + tx * 4]);
        unsigned int av[4] = {a4.x, a4.y, a4.z, a4.w};
        unsigned int wv[4] = {w4.x, w4.y, w4.z, w4.w};
        #pragma unroll
        for (int r = 0; r < 4; ++r)
            #pragma unroll
            for (int c = 0; c < 4; ++c)
                acc2[r][c] = fdot2f(av[r], wv[c], acc2[r][c]);
    }
    #pragma unroll
    for (int r = 0; r < 4; ++r) {
        int row = r0 + ty * 4 + r;
        if (row < n) {
            float di = dinv[row];
            __half2 q0 = __floats2half2_rn(acc2[r][0] * di, acc2[r][1] * di);
            __half2 q1 = __floats2half2_rn(acc2[r][2] * di, acc2[r][3] * di);
            uint2 o;
            o.x = __builtin_bit_cast(unsigned int, q0);
            o.y = __builtin_bit_cast(unsigned int, q1);
            *reinterpret_cast<uint2*>(hs2h + (size_t)row * 64 + tx * 4) = o;
        }
    }
}

extern "C" void kernel_launch(void* const* d_in, const int* in_sizes, int n_in,
                              void* d_out, int out_size, void* d_ws, size_t ws_size,
                              hipStream_t stream) {
    const float* x  = (const float*)d_in[0];
    const int*   ei = (const int*)d_in[1];
    const float* W1 = (const float*)d_in[2];
    const float* b1 = (const float*)d_in[3];
    const float* W2 = (const float*)d_in[4];
    const float* b2 = (const float*)d_in[5];
    float* out = (float*)d_out;

    const int n = in_sizes[0] / 64;     // 50000 (< 65536 -> uint16 indices valid)
    const int E = in_sizes[1] / 2;      // 800000
    const int* src = ei;
    const int* dst = ei + E;

    const int NB = divup(E, EPB);         // 196 bin blocks
    const int nbuck = divup(n, 1 << BSH); // 196 buckets

    char* ws = (char*)d_ws;
    size_t off = 0;
    auto alloc = [&](size_t bytes) { void* p = ws + off; off = (off + bytes + 255) & ~(size_t)255; return p; };
    int*    cnt     = (int*)   alloc((size_t)n * 4);
    float*  dinv    = (float*) alloc((size_t)n * 4);
    int2*   staging = (int2*)  alloc((size_t)NB * EPB * 8);   // 6.4 MB
    int*    runoff  = (int*)   alloc((size_t)nbuck * NB * 4);
    int*    runlen  = (int*)   alloc((size_t)nbuck * NB * 4);
    unsigned short* eidx = (unsigned short*)alloc((size_t)n * CAP * 2);  // 6.4 MB uint16
    __half* xh      = (__half*)alloc((size_t)n * 64 * 2);     // 6.4 MB fp16 payload
    __half* axh     = (__half*)alloc((size_t)n * 64 * 2);     // 6.4 MB aggregated x (fp16)
    unsigned int* w1p = (unsigned int*)alloc(32 * 128 * 4);
    unsigned int* w2p = (unsigned int*)alloc(64 * 64 * 4);
    __half* hs2h    = xh;     // xh dead after layer-1 agg; reuse (mlp r/w distinct rows 1:1)

    // adjacency build (+weight packing in extra block) + fused x*dinv -> fp16
    k_bin  <<<NB + 1, 256, 0, stream>>>(src, dst, staging, runoff, runlen, W1, W2, w1p, w2p, E, nbuck, NB);
    k_build<<<nbuck, 256, 0, stream>>>(staging, runoff, runlen, x, eidx, cnt, dinv, xh, n, NB);

    // layer 1 aggregate (fp16 out)
    k_aggh<false><<<divup(n * 8, 256), 256, 0, stream>>>(cnt, eidx, xh, dinv, nullptr, axh, n);

    // fused MLP: relu(axh@W1+b1)@W2 * dinv -> fp16
    k_mlp<<<divup(n, 64), 256, 0, stream>>>(axh, w1p, w2p, b1, dinv, hs2h, n);

    // layer 2 aggregate (fp32 out + bias + relu)
    k_aggh<true><<<divup(n * 8, 256), 256, 0, stream>>>(cnt, eidx, hs2h, dinv, b2, out, n);
}

// Round 16
// 99.941 us; speedup vs baseline: 1.0395x; 1.0017x over previous
//
#include <hip/hip_runtime.h>
#include <hip/hip_fp16.h>
#include <cstddef>
#include <cstdint>

static inline int divup(int a, int b) { return (a + b - 1) / b; }

#define CAP 64        // per-node bucket capacity; P(deg>=64) ~ 1e-19 for Poisson(16)
#define EPB 4096      // edges per bin-block (16/thread @ 256 threads)
#define BSH 8         // bucket shift: bucket = dst >> 8 (256 nodes/bucket)

typedef _Float16 h2v __attribute__((ext_vector_type(2)));

// fp16x2 dot with fp32 accumulate (v_dot2_f32_f16); fallback = unpack + 2 fmaf
__device__ inline float fdot2f(unsigned int a, unsigned int b, float c) {
#if __has_builtin(__builtin_amdgcn_fdot2)
    return __builtin_amdgcn_fdot2(__builtin_bit_cast(h2v, a),
                                  __builtin_bit_cast(h2v, b), c, false);
#else
    __half2 ha = __builtin_bit_cast(__half2, a);
    __half2 hb = __builtin_bit_cast(__half2, b);
    float2 fa = __half22float2(ha), fb = __half22float2(hb);
    return fmaf(fa.y, fb.y, fmaf(fa.x, fb.x, c));
#endif
}

// Phase 1: block-local binning. Edges packed to u32 (src:u16 | dst_local:u8<<16;
// bucket implicit in run) and sorted by coarse bucket into a 16KB LDS tile,
// then dumped COALESCED to the block's private staging region.
// Block NB (extra) packs W1/W2 into k-pair half2 (fused weight conversion).
__global__ __launch_bounds__(256) void k_bin(const int* __restrict__ src,
                                             const int* __restrict__ dst,
                                             unsigned int* __restrict__ staging,
                                             int* __restrict__ runoff,
                                             int* __restrict__ runlen,
                                             const float* __restrict__ W1,
                                             const float* __restrict__ W2,
                                             unsigned int* __restrict__ w1p,
                                             unsigned int* __restrict__ w2p,
                                             int E, int nbuck, int NB) {
    const int t = threadIdx.x;
    const int blk = blockIdx.x;
    if (blk == NB) {                       // weight-packing block
        for (int i = t; i < 32 * 128 + 64 * 64; i += 256) {
            if (i < 32 * 128) {
                int kp = i >> 7, c = i & 127;
                __half2 h = __floats2half2_rn(W1[(size_t)(2 * kp) * 128 + c],
                                              W1[(size_t)(2 * kp + 1) * 128 + c]);
                w1p[i] = __builtin_bit_cast(unsigned int, h);
            } else {
                int j = i - 32 * 128;
                int kp = j >> 6, c = j & 63;
                __half2 h = __floats2half2_rn(W2[(size_t)(2 * kp) * 64 + c],
                                              W2[(size_t)(2 * kp + 1) * 64 + c]);
                w2p[j] = __builtin_bit_cast(unsigned int, h);
            }
        }
        return;
    }
    __shared__ int hist[256];
    __shared__ int scan[256];
    __shared__ unsigned int sstage[EPB];  // 16 KiB block-local packed edges
    const int e0 = blk * EPB;

    unsigned int pk[16];
    int cb[16];
    #pragma unroll
    for (int j = 0; j < 16; ++j) {
        int idx = e0 + j * 256 + t;
        if (idx < E) {
            int s = src[idx], d = dst[idx];
            cb[j] = d >> BSH;
            pk[j] = (unsigned int)(s & 0xFFFF) | ((unsigned int)(d & 0xFF) << 16);
        } else {
            cb[j] = -1;
        }
    }
    hist[t] = 0;
    __syncthreads();
    #pragma unroll
    for (int j = 0; j < 16; ++j)
        if (cb[j] >= 0) atomicAdd(&hist[cb[j]], 1);
    __syncthreads();
    scan[t] = hist[t];
    __syncthreads();
    for (int d = 1; d < 256; d <<= 1) {
        int v = (t >= d) ? scan[t - d] : 0;
        __syncthreads();
        scan[t] += v;
        __syncthreads();
    }
    int base = scan[t] - hist[t];
    if (t < nbuck) {
        runoff[t * NB + blk] = base;
        runlen[t * NB + blk] = hist[t];
    }
    hist[t] = base;
    __syncthreads();
    #pragma unroll
    for (int j = 0; j < 16; ++j) {
        if (cb[j] >= 0) {
            int p = atomicAdd(&hist[cb[j]], 1);
            sstage[p] = pk[j];            // LDS scatter (cheap)
        }
    }
    __syncthreads();
    // coalesced dump: 16KB as uint4 stream
    uint4* gout = reinterpret_cast<uint4*>(staging + (size_t)blk * EPB);
    const uint4* sin = reinterpret_cast<const uint4*>(sstage);
    for (int i = t; i < EPB / 4; i += 256) gout[i] = sin[i];
}

// Phase 2: one block per bucket. Process the NB runs directly (8 runs x 32
// lanes, coalesced u32 reads), unpack (src u16, dst_local u8), scatter src
// into eidx16[node*CAP+p] (uint16, single-writer lines), emit cnt/dinv,
// fused xh = half(x * dinv).
__global__ __launch_bounds__(256) void k_build(const unsigned int* __restrict__ staging,
                                               const int* __restrict__ runoff,
                                               const int* __restrict__ runlen,
                                               const float* __restrict__ x,
                                               unsigned short* __restrict__ eidx,
                                               int* __restrict__ cnt,
                                               float* __restrict__ dinv,
                                               __half* __restrict__ xh,
                                               int n, int NB) {
    __shared__ int runbase_l[512];
    __shared__ int runlen_l[512];
    __shared__ int cnt_l[256];
    __shared__ float sdinv[256];
    const int t = threadIdx.x;
    const int b = blockIdx.x;
    const int node0 = b << BSH;

    for (int r = t; r < NB; r += 256) {
        runbase_l[r] = runoff[b * NB + r];
        runlen_l[r]  = runlen[b * NB + r];
    }
    cnt_l[t] = 0;
    __syncthreads();
    const int lane = t & 31;
    for (int rb = t >> 5; rb < NB; rb += 8) {      // 8 runs in parallel, 32 lanes each
        const unsigned int* sp = staging + (size_t)rb * EPB + runbase_l[rb];
        const int len = runlen_l[rb];
        for (int i = lane; i < len; i += 32) {
            unsigned int w = sp[i];
            int local = (w >> 16) & 0xFF;
            int p = atomicAdd(&cnt_l[local], 1);
            if (p < CAP) eidx[(size_t)(node0 + local) * CAP + p] = (unsigned short)(w & 0xFFFF);
        }
    }
    __syncthreads();
    int node = node0 + t;
    float di_t = rsqrtf((float)(cnt_l[t] + 1));
    sdinv[t] = di_t;
    if (node < n) {
        cnt[node] = cnt_l[t];
        dinv[node] = di_t;
    }
    __syncthreads();
    for (int i = t; i < 256 * 16; i += 256) {
        int lr = i >> 4, c4 = (i & 15) * 4;
        int nd = node0 + lr;
        if (nd < n) {
            float4 v = *reinterpret_cast<const float4*>(x + (size_t)nd * 64 + c4);
            float di = sdinv[lr];
            __half2 h0 = __floats2half2_rn(v.x * di, v.y * di);
            __half2 h1 = __floats2half2_rn(v.z * di, v.w * di);
            *reinterpret_cast<__half2*>(xh + (size_t)nd * 64 + c4)     = h0;
            *reinterpret_cast<__half2*>(xh + (size_t)nd * 64 + c4 + 2) = h1;
        }
    }
}

__device__ inline void acc8(uint4 u, float a[8]) {
    float2 f0 = __half22float2(*reinterpret_cast<const __half2*>(&u.x));
    float2 f1 = __half22float2(*reinterpret_cast<const __half2*>(&u.y));
    float2 f2 = __half22float2(*reinterpret_cast<const __half2*>(&u.z));
    float2 f3 = __half22float2(*reinterpret_cast<const __half2*>(&u.w));
    a[0] += f0.x; a[1] += f0.y; a[2] += f1.x; a[3] += f1.y;
    a[4] += f2.x; a[5] += f2.y; a[6] += f3.x; a[7] += f3.y;
}

// Row-parallel aggregation over fp16 64-col data: 8 lanes/node, 16B/lane.
// FINAL=false: axh(fp16) = (self + sum_neighbors) * dinv       (layer-1 pre-GEMM)
// FINAL=true : out(fp32) = relu((self + sum) * dinv + bias)    (layer-2 output)
template <bool FINAL>
__global__ __launch_bounds__(256) void k_aggh(const int* __restrict__ cnt,
                                              const unsigned short* __restrict__ eidx,
                                              const __half* __restrict__ in16,
                                              const float* __restrict__ dinv,
                                              const float* __restrict__ bias,
                                              void* __restrict__ outp, int n) {
    int t = blockIdx.x * blockDim.x + threadIdx.x;
    int node = t >> 3;
    if (node >= n) return;
    int lane = t & 7;
    const int hoff = lane * 8;
    float a[8] = {0.f, 0.f, 0.f, 0.f, 0.f, 0.f, 0.f, 0.f};
    acc8(*reinterpret_cast<const uint4*>(in16 + (size_t)node * 64 + hoff), a);  // self
    const int b = node * CAP;
    const int eN = b + min(cnt[node], CAP);
    int e = b;
    for (; e + 4 <= eN; e += 4) {
        uint2 u = *reinterpret_cast<const uint2*>(eidx + e);   // 4 uint16 indices
        int s0 = u.x & 0xFFFF, s1 = u.x >> 16;
        int s2 = u.y & 0xFFFF, s3 = u.y >> 16;
        uint4 u0 = *reinterpret_cast<const uint4*>(in16 + (size_t)s0 * 64 + hoff);
        uint4 u1 = *reinterpret_cast<const uint4*>(in16 + (size_t)s1 * 64 + hoff);
        uint4 u2 = *reinterpret_cast<const uint4*>(in16 + (size_t)s2 * 64 + hoff);
        uint4 u3 = *reinterpret_cast<const uint4*>(in16 + (size_t)s3 * 64 + hoff);
        acc8(u0, a); acc8(u1, a); acc8(u2, a); acc8(u3, a);
    }
    for (; e < eN; ++e) {
        int s = eidx[e];
        acc8(*reinterpret_cast<const uint4*>(in16 + (size_t)s * 64 + hoff), a);
    }
    float di = dinv[node];
    if (FINAL) {
        float* out64 = (float*)outp;
        float4 r0, r1;
        const float4 b0 = *reinterpret_cast<const float4*>(bias + hoff);
        const float4 b1 = *reinterpret_cast<const float4*>(bias + hoff + 4);
        r0.x = fmaxf(fmaf(a[0], di, b0.x), 0.f); r0.y = fmaxf(fmaf(a[1], di, b0.y), 0.f);
        r0.z = fmaxf(fmaf(a[2], di, b0.z), 0.f); r0.w = fmaxf(fmaf(a[3], di, b0.w), 0.f);
        r1.x = fmaxf(fmaf(a[4], di, b1.x), 0.f); r1.y = fmaxf(fmaf(a[5], di, b1.y), 0.f);
        r1.z = fmaxf(fmaf(a[6], di, b1.z), 0.f); r1.w = fmaxf(fmaf(a[7], di, b1.w), 0.f);
        *reinterpret_cast<float4*>(out64 + (size_t)node * 64 + hoff)     = r0;
        *reinterpret_cast<float4*>(out64 + (size_t)node * 64 + hoff + 4) = r1;
    } else {
        unsigned int* out16 = (unsigned int*)outp;  // fp16 row-major, as uints
        __half2 p0 = __floats2half2_rn(a[0] * di, a[1] * di);
        __half2 p1 = __floats2half2_rn(a[2] * di, a[3] * di);
        __half2 p2 = __floats2half2_rn(a[4] * di, a[5] * di);
        __half2 p3 = __floats2half2_rn(a[6] * di, a[7] * di);
        uint4 o;
        o.x = __builtin_bit_cast(unsigned int, p0);
        o.y = __builtin_bit_cast(unsigned int, p1);
        o.z = __builtin_bit_cast(unsigned int, p2);
        o.w = __builtin_bit_cast(unsigned int, p3);
        *reinterpret_cast<uint4*>(out16 + (size_t)node * 32 + lane * 4) = o;
    }
}

// Fused MLP: hs2h = half( relu(axh @ W1 + b1) @ W2 * dinv[row] )
// 64-row block, 256 threads; fp16 operands (k-pair half2), fp32 accumulate.
// h1 never leaves LDS. sA/sH share one 17KB LDS buffer -> 49KB, 3 blocks/CU.
__global__ __launch_bounds__(256) void k_mlp(const __half* __restrict__ axh,
                                             const unsigned int* __restrict__ w1p,
                                             const unsigned int* __restrict__ w2p,
                                             const float* __restrict__ b1,
                                             const float* __restrict__ dinv,
                                             __half* __restrict__ hs2h, int n) {
    __shared__ unsigned int sW1[32 * 128];   // 16 KiB [kp][c]
    __shared__ unsigned int sW2[64 * 64];    // 16 KiB [kp][c]
    __shared__ unsigned int sAH[64 * 68];    // 17 KiB union: sA (first 32*68) then sH
    const int t = threadIdx.x;
    const int r0 = blockIdx.x * 64;
    {
        uint4* d1 = reinterpret_cast<uint4*>(sW1);
        const uint4* s1 = reinterpret_cast<const uint4*>(w1p);
        for (int i = t; i < 1024; i += 256) d1[i] = s1[i];
        uint4* d2 = reinterpret_cast<uint4*>(sW2);
        const uint4* s2 = reinterpret_cast<const uint4*>(w2p);
        for (int i = t; i < 1024; i += 256) d2[i] = s2[i];
    }
    const unsigned int* axu = reinterpret_cast<const unsigned int*>(axh);
    for (int i = t; i < 2048; i += 256) {            // transpose A tile: [row][kp] -> [kp][row]
        int row = i >> 5, kp = i & 31;
        int gr = r0 + row;
        sAH[kp * 68 + row] = (gr < n) ? axu[(size_t)gr * 32 + kp] : 0u;
    }
    __syncthreads();
    const int tx = t & 15, ty = t >> 4;
    float acc[4][8] = {};
    #pragma unroll 8
    for (int kp = 0; kp < 32; ++kp) {
        uint4 a4 = *reinterpret_cast<const uint4*>(&sAH[kp * 68 + ty * 4]);
        uint4 wA = *reinterpret_cast<const uint4*>(&sW1[kp * 128 + tx * 4]);
        uint4 wB = *reinterpret_cast<const uint4*>(&sW1[kp * 128 + 64 + tx * 4]);
        unsigned int av[4] = {a4.x, a4.y, a4.z, a4.w};
        unsigned int wv[8] = {wA.x, wA.y, wA.z, wA.w, wB.x, wB.y, wB.z, wB.w};
        #pragma unroll
        for (int r = 0; r < 4; ++r)
            #pragma unroll
            for (int c = 0; c < 8; ++c)
                acc[r][c] = fdot2f(av[r], wv[c], acc[r][c]);
    }
    __syncthreads();                                 // all sA reads done before sH overwrite
    const float4 bb0 = *reinterpret_cast<const float4*>(b1 + tx * 4);
    const float4 bb1 = *reinterpret_cast<const float4*>(b1 + 64 + tx * 4);
    #pragma unroll
    for (int r = 0; r < 4; ++r) {
        int row = ty * 4 + r;
        float h0 = fmaxf(acc[r][0] + bb0.x, 0.f), h1 = fmaxf(acc[r][1] + bb0.y, 0.f);
        float h2 = fmaxf(acc[r][2] + bb0.z, 0.f), h3 = fmaxf(acc[r][3] + bb0.w, 0.f);
        float h4 = fmaxf(acc[r][4] + bb1.x, 0.f), h5 = fmaxf(acc[r][5] + bb1.y, 0.f);
        float h6 = fmaxf(acc[r][6] + bb1.z, 0.f), h7 = fmaxf(acc[r][7] + bb1.w, 0.f);
        __half2 p;
        p = __floats2half2_rn(h0, h1); sAH[(2 * tx + 0) * 68 + row]  = __builtin_bit_cast(unsigned int, p);
        p = __floats2half2_rn(h2, h3); sAH[(2 * tx + 1) * 68 + row]  = __builtin_bit_cast(unsigned int, p);
        p = __floats2half2_rn(h4, h5); sAH[(32 + 2 * tx) * 68 + row] = __builtin_bit_cast(unsigned int, p);
        p = __floats2half2_rn(h6, h7); sAH[(33 + 2 * tx) * 68 + row] = __builtin_bit_cast(unsigned int, p);
    }
    __syncthreads();
    float acc2[4][4] = {};
    #pragma unroll 8
    for (int kp = 0; kp < 64; ++kp) {
        uint4 a4 = *reinterpret_cast<const uint4*>(&sAH[kp * 68 + ty * 4]);
        uint4 w4 = *reinterpret_cast<const uint4*>(&sW2[kp * 64 + tx * 4]);
        unsigned int av[4] = {a4.x, a4.y, a4.z, a4.w};
        unsigned int wv[4] = {w4.x, w4.y, w4.z, w4.w};
        #pragma unroll
        for (int r = 0; r < 4; ++r)
            #pragma unroll
            for (int c = 0; c < 4; ++c)
                acc2[r][c] = fdot2f(av[r], wv[c], acc2[r][c]);
    }
    #pragma unroll
    for (int r = 0; r < 4; ++r) {
        int row = r0 + ty * 4 + r;
        if (row < n) {
            float di = dinv[row];
            __half2 q0 = __floats2half2_rn(acc2[r][0] * di, acc2[r][1] * di);
            __half2 q1 = __floats2half2_rn(acc2[r][2] * di, acc2[r][3] * di);
            uint2 o;
            o.x = __builtin_bit_cast(unsigned int, q0);
            o.y = __builtin_bit_cast(unsigned int, q1);
            *reinterpret_cast<uint2*>(hs2h + (size_t)row * 64 + tx * 4) = o;
        }
    }
}

extern "C" void kernel_launch(void* const* d_in, const int* in_sizes, int n_in,
                              void* d_out, int out_size, void* d_ws, size_t ws_size,
                              hipStream_t stream) {
    const float* x  = (const float*)d_in[0];
    const int*   ei = (const int*)d_in[1];
    const float* W1 = (const float*)d_in[2];
    const float* b1 = (const float*)d_in[3];
    const float* W2 = (const float*)d_in[4];
    const float* b2 = (const float*)d_in[5];
    float* out = (float*)d_out;

    const int n = in_sizes[0] / 64;     // 50000 (< 65536 -> uint16 src/idx valid)
    const int E = in_sizes[1] / 2;      // 800000
    const int* src = ei;
    const int* dst = ei + E;

    const int NB = divup(E, EPB);         // 196 bin blocks
    const int nbuck = divup(n, 1 << BSH); // 196 buckets

    char* ws = (char*)d_ws;
    size_t off = 0;
    auto alloc = [&](size_t bytes) { void* p = ws + off; off = (off + bytes + 255) & ~(size_t)255; return p; };
    int*    cnt     = (int*)   alloc((size_t)n * 4);
    float*  dinv    = (float*) alloc((size_t)n * 4);
    unsigned int* staging = (unsigned int*)alloc((size_t)NB * EPB * 4);  // 3.2 MB packed
    int*    runoff  = (int*)   alloc((size_t)nbuck * NB * 4);
    int*    runlen  = (int*)   alloc((size_t)nbuck * NB * 4);
    unsigned short* eidx = (unsigned short*)alloc((size_t)n * CAP * 2);  // 6.4 MB uint16
    __half* xh      = (__half*)alloc((size_t)n * 64 * 2);     // 6.4 MB fp16 payload
    __half* axh     = (__half*)alloc((size_t)n * 64 * 2);     // 6.4 MB aggregated x (fp16)
    unsigned int* w1p = (unsigned int*)alloc(32 * 128 * 4);
    unsigned int* w2p = (unsigned int*)alloc(64 * 64 * 4);
    __half* hs2h    = xh;     // xh dead after layer-1 agg; reuse (mlp r/w distinct rows 1:1)

    // adjacency build (+weight packing in extra block) + fused x*dinv -> fp16
    k_bin  <<<NB + 1, 256, 0, stream>>>(src, dst, staging, runoff, runlen, W1, W2, w1p, w2p, E, nbuck, NB);
    k_build<<<nbuck, 256, 0, stream>>>(staging, runoff, runlen, x, eidx, cnt, dinv, xh, n, NB);

    // layer 1 aggregate (fp16 out)
    k_aggh<false><<<divup(n * 8, 256), 256, 0, stream>>>(cnt, eidx, xh, dinv, nullptr, axh, n);

    // fused MLP: relu(axh@W1+b1)@W2 * dinv -> fp16
    k_mlp<<<divup(n, 64), 256, 0, stream>>>(axh, w1p, w2p, b1, dinv, hs2h, n);

    // layer 2 aggregate (fp32 out + bias + relu)
    k_aggh<true><<<divup(n * 8, 256), 256, 0, stream>>>(cnt, eidx, hs2h, dinv, b2, out, n);
}